// Round 1
// baseline (67.622 us; speedup 1.0000x reference)
//
#include <hip/hip_runtime.h>

// Problem: ctx[b,i,d] = tanh(emb[b,i,d] * mean_j emb[b,j,d])
// B=512, I=128, D=64, fp32 in / fp32 out. Memory-bound: 33.5 MB total traffic.

#define BB 512
#define II 128
#define DD 64
#define ELEMS_PER_BATCH (II * DD)      // 8192 floats
#define VEC_PER_BATCH   (ELEMS_PER_BATCH / 4)  // 2048 float4
#define BLOCK 256
#define VEC_PER_THREAD  (VEC_PER_BATCH / BLOCK) // 8

__device__ __forceinline__ float fast_tanh(float x) {
    // tanh(x) = 1 - 2/(e^{2x}+1). v_exp_f32 + v_rcp_f32, ~1ulp each.
    // x -> +inf: e=inf, rcp=0 -> 1.  x -> -inf: e=0, rcp(1)=1 -> -1.
    float e = __expf(2.0f * x);
    return __fmaf_rn(-2.0f, __builtin_amdgcn_rcpf(e + 1.0f), 1.0f);
}

__global__ __launch_bounds__(BLOCK) void ctx_tanh_kernel(
        const float* __restrict__ emb, float* __restrict__ out) {
    __shared__ float4 s_emb[VEC_PER_BATCH];  // 32 KiB: batch's full tile
    __shared__ float4 s_part[BLOCK];         // 4 KiB: per-thread column partials
    __shared__ float4 s_mean[16];            // 64 mean values as 16 float4

    const int b = blockIdx.x;
    const int t = threadIdx.x;
    const float4* __restrict__ gin  = (const float4*)(emb + (size_t)b * ELEMS_PER_BATCH);
    float4* __restrict__       gout = (float4*)(out + (size_t)b * ELEMS_PER_BATCH);

    // Phase 1: coalesced load -> LDS stash + per-thread column partial sum.
    // j = t + 256*k  =>  j % 16 == t % 16, so d_base = 4*(t%16) is k-invariant.
    float4 acc = make_float4(0.f, 0.f, 0.f, 0.f);
    #pragma unroll
    for (int k = 0; k < VEC_PER_THREAD; ++k) {
        int j = t + BLOCK * k;
        float4 v = gin[j];
        s_emb[j] = v;
        acc.x += v.x; acc.y += v.y; acc.z += v.z; acc.w += v.w;
    }
    s_part[t] = acc;
    __syncthreads();

    // Phase 2: 16 threads reduce 16 partials each -> mean[d] (d = 4g..4g+3).
    if (t < 16) {
        float4 s = make_float4(0.f, 0.f, 0.f, 0.f);
        #pragma unroll
        for (int m = 0; m < 16; ++m) {
            float4 p = s_part[m * 16 + t];
            s.x += p.x; s.y += p.y; s.z += p.z; s.w += p.w;
        }
        const float inv = 1.0f / (float)II;
        s.x *= inv; s.y *= inv; s.z *= inv; s.w *= inv;
        s_mean[t] = s;
    }
    __syncthreads();

    // Phase 3: apply mean-scale + tanh from LDS, coalesced float4 stores.
    #pragma unroll
    for (int k = 0; k < VEC_PER_THREAD; ++k) {
        int j = t + BLOCK * k;
        float4 v = s_emb[j];
        float4 m = s_mean[j & 15];
        float4 o;
        o.x = fast_tanh(v.x * m.x);
        o.y = fast_tanh(v.y * m.y);
        o.z = fast_tanh(v.z * m.z);
        o.w = fast_tanh(v.w * m.w);
        gout[j] = o;
    }
}

extern "C" void kernel_launch(void* const* d_in, const int* in_sizes, int n_in,
                              void* d_out, int out_size, void* d_ws, size_t ws_size,
                              hipStream_t stream) {
    const float* emb = (const float*)d_in[0];
    float* out = (float*)d_out;
    ctx_tanh_kernel<<<dim3(BB), dim3(BLOCK), 0, stream>>>(emb, out);
}